// Round 14
// baseline (1882.934 us; speedup 1.0000x reference)
//
#include <hip/hip_runtime.h>
#include <cmath>

#define NN 100000
#define EE 1600000
#define H 128
#define PP 16
#define S1 136   // LDS A-stride (halfwords)
#define SCB 4096 // scan elements per block

typedef __attribute__((ext_vector_type(8))) short bf16x8;
typedef __attribute__((ext_vector_type(4))) float f32x4;

__device__ __forceinline__ ushort f2b(float f){
  union{float f; unsigned u;} x; x.f=f;
  unsigned r=(x.u + 0x7fffu + ((x.u>>16)&1u))>>16;
  return (ushort)r;
}
__device__ __forceinline__ float b2f(ushort h){
  union{unsigned u; float f;} x; x.u=((unsigned)h)<<16; return x.f;
}
__device__ __forceinline__ unsigned pack2(float a, float b){
  return (unsigned)f2b(a) | ((unsigned)f2b(b)<<16);
}

// ---- fused weight fp32->bf16 conversion (single launch, 10 segments)
struct CvtArgs {
  const float* src[10];
  ushort* dst[10];
  int off[11];
};
__global__ void cvtall_kernel(CvtArgs a){
  int i=blockIdx.x*256+threadIdx.x;
  if (i>=a.off[10]) return;
  int s=0;
  #pragma unroll
  for (int k=1;k<10;k++) if (i>=a.off[k]) s=k;
  int local=i-a.off[s];
  a.dst[s][local]=f2b(a.src[s][local]);
}

// ---- edge_index dtype detect: flag=1 if int64 (odd words all zero), else 0
__global__ void detect_kernel(const int* __restrict__ ei, int* __restrict__ flag){
  __shared__ int nz;
  if (threadIdx.x==0) nz=0;
  __syncthreads();
  for (int i=threadIdx.x; i<2048; i+=256){
    if (ei[2*i+1]!=0) nz=1;
  }
  __syncthreads();
  if (threadIdx.x==0) flag[0] = nz ? 0 : 1;
}

// ---- MFMA encoder: tokens[n,0,:] = LN(x @ enc_w^T + enc_b); 128 nodes/block
__global__ __launch_bounds__(512) void enc2_kernel(
    const float* __restrict__ x, const ushort* __restrict__ wenc,
    const float* __restrict__ enc_b,
    const float* __restrict__ g, const float* __restrict__ bb,
    ushort* __restrict__ tokens){
  __shared__ __align__(16) ushort bufA[128*S1];
  const int tid=threadIdx.x;
  const int wid=tid>>6;
  const int l=tid&63, l15=l&15, l4=(l>>4)&3;
  const int node0=blockIdx.x*128;
  const int rowb=wid*16 + l4*4;

  { int rr=tid>>2, seg=tid&3;
    int node=node0+rr; if (node>=NN) node=NN-1;
    const float4* xr=(const float4*)(x+(size_t)node*H+seg*32);
    #pragma unroll
    for (int i=0;i<8;i++){
      float4 v=xr[i];
      *(unsigned*)(bufA + rr*S1 + seg*32 + i*4)   = pack2(v.x,v.y);
      *(unsigned*)(bufA + rr*S1 + seg*32 + i*4+2) = pack2(v.z,v.w);
    }
  }
  __syncthreads();

  bf16x8 a[4];
  #pragma unroll
  for (int kk=0;kk<4;kk++)
    a[kk]=*(const bf16x8*)(bufA + (wid*16+l15)*S1 + kk*32 + l4*8);
  float acc[8][4];
  #pragma unroll
  for (int nt=0;nt<8;nt++){
    int n=nt*16+l15;
    f32x4 c={0.f,0.f,0.f,0.f};
    #pragma unroll
    for (int kk=0;kk<4;kk++){
      bf16x8 bbf=*(const bf16x8*)(wenc + (size_t)n*H + kk*32 + l4*8);
      c=__builtin_amdgcn_mfma_f32_16x16x32_bf16(a[kk],bbf,c,0,0,0);
    }
    float bv=enc_b[n];
    #pragma unroll
    for (int reg=0;reg<4;reg++) acc[nt][reg]=c[reg]+bv;
  }
  float gv[8], bvv[8];
  #pragma unroll
  for (int nt=0;nt<8;nt++){ gv[nt]=g[nt*16+l15]; bvv[nt]=bb[nt*16+l15]; }
  #pragma unroll
  for (int reg=0;reg<4;reg++){
    float s=0.f,q=0.f;
    #pragma unroll
    for (int nt=0;nt<8;nt++){ float v=acc[nt][reg]; s+=v; q+=v*v; }
    #pragma unroll
    for (int m=1;m<16;m<<=1){ s+=__shfl_xor(s,m); q+=__shfl_xor(q,m); }
    float mean=s*(1.f/128.f);
    float rs=rsqrtf(q*(1.f/128.f)-mean*mean+1e-5f);
    int node=node0+rowb+reg;
    if (node<NN){
      #pragma unroll
      for (int nt=0;nt<8;nt++)
        tokens[(size_t)node*4*H + nt*16+l15]=f2b((acc[nt][reg]-mean)*rs*gv[nt]+bvv[nt]);
    }
  }
}

// ---- histograms
__global__ void hist_kernel(const int* __restrict__ ei, const int* __restrict__ flag,
                            float* __restrict__ deg, int* __restrict__ counts){
  int f=flag[0];
  int e=blockIdx.x*256+threadIdx.x;
  if (e>=EE) return;
  int rw=ei[(size_t)e<<f];
  int cl=ei[((size_t)EE+e)<<f];
  atomicAdd(&counts[rw],1);
  atomicAdd(&deg[cl],1.0f);
}

__global__ void dinv_kernel(float* __restrict__ deg){
  int i=blockIdx.x*256+threadIdx.x;
  if (i<NN) deg[i]=rsqrtf(fmaxf(deg[i],1.0f));
}

// ---- multi-block scan: phase 1 = per-block sums
__global__ __launch_bounds__(1024) void scanp1_kernel(const int* __restrict__ counts,
                                                      int* __restrict__ bsum){
  int b=blockIdx.x, tid=threadIdx.x;
  int base=b*SCB;
  int s=0;
  for (int i=tid;i<SCB;i+=1024){
    int idx=base+i;
    s += (idx<NN)?counts[idx]:0;
  }
  s+=__shfl_xor(s,32); s+=__shfl_xor(s,16); s+=__shfl_xor(s,8);
  s+=__shfl_xor(s,4);  s+=__shfl_xor(s,2);  s+=__shfl_xor(s,1);
  __shared__ int ws[16];
  if ((tid&63)==0) ws[tid>>6]=s;
  __syncthreads();
  if (tid==0){
    int t=0;
    #pragma unroll
    for (int w=0;w<16;w++) t+=ws[w];
    bsum[b]=t;
  }
}
// ---- phase 2: serial exclusive scan of block sums (tiny) + total -> row_ptr[NN]
__global__ void scanp2_kernel(int* __restrict__ bsum, int nb, int* __restrict__ row_ptr){
  if (threadIdx.x==0 && blockIdx.x==0){
    int acc=0;
    for (int i=0;i<nb;i++){ int v=bsum[i]; bsum[i]=acc; acc+=v; }
    bsum[nb]=acc;
    row_ptr[NN]=acc;
  }
}
// ---- phase 3: per-block exclusive scan + offset -> row_ptr, cursor
__global__ __launch_bounds__(1024) void scanp3_kernel(const int* __restrict__ counts,
                                                      const int* __restrict__ bsum,
                                                      int* __restrict__ row_ptr,
                                                      int* __restrict__ cursor){
  int b=blockIdx.x;
  int tid=threadIdx.x, lane=tid&63, w=tid>>6;
  __shared__ int ws[16];
  __shared__ int carry_s;
  if (tid==0) carry_s=bsum[b];
  __syncthreads();
  int base=b*SCB;
  for (int it=0; it<SCB; it+=1024){
    int i=base+it+tid;
    int v=(i<NN)?counts[i]:0;
    int x=v;
    for (int off=1; off<64; off<<=1){
      int t=__shfl_up(x,off);
      if (lane>=off) x+=t;
    }
    if (lane==63) ws[w]=x;
    __syncthreads();
    int woff=0;
    #pragma unroll
    for (int ww=0; ww<16; ww++) if (ww<w) woff+=ws[ww];
    int carry=carry_s;
    int excl=carry+woff+x-v;
    if (i<NN){ row_ptr[i]=excl; cursor[i]=excl; }
    __syncthreads();
    if (tid==1023) carry_s = carry + woff + x;
    __syncthreads();
  }
}

// ---- scatter edges into CSR
__global__ void scatter_kernel(const int* __restrict__ ei, const int* __restrict__ flag,
                               int* __restrict__ cursor, const float* __restrict__ dinv,
                               int* __restrict__ cs_col, float* __restrict__ cs_w){
  int f=flag[0];
  int e=blockIdx.x*256+threadIdx.x;
  if (e>=EE) return;
  int rw=ei[(size_t)e<<f];
  int cl=ei[((size_t)EE+e)<<f];
  int pos=atomicAdd(&cursor[rw],1);
  cs_col[pos]=cl;
  cs_w[pos]=dinv[rw]*dinv[cl];
}

// ---- SpMM hop v2: 32 lanes per node, 8B per lane; 8 nodes/block
__global__ __launch_bounds__(256) void spmm2_kernel(ushort* __restrict__ tokens,
    const int* __restrict__ row_ptr, const int* __restrict__ cs_col,
    const float* __restrict__ cs_w, int k){
  int tid=threadIdx.x;
  int nl=tid>>5;
  int sub=tid&31;
  int n=blockIdx.x*8+nl;
  int beg=row_ptr[n], end=row_ptr[n+1];
  float a0=0.f,a1=0.f,a2=0.f,a3=0.f;
  const ushort* src=tokens+(size_t)k*H+sub*4;
  int j=beg;
  for (; j+8<=end; j+=8){
    int   c[8]; float w[8]; unsigned long long v[8];
    #pragma unroll
    for (int u=0;u<8;u++){ c[u]=cs_col[j+u]; w[u]=cs_w[j+u]; }
    #pragma unroll
    for (int u=0;u<8;u++) v[u]=*(const unsigned long long*)(src+(size_t)c[u]*(4*H));
    #pragma unroll
    for (int u=0;u<8;u++){
      a0+=w[u]*b2f((ushort)(v[u]));
      a1+=w[u]*b2f((ushort)(v[u]>>16));
      a2+=w[u]*b2f((ushort)(v[u]>>32));
      a3+=w[u]*b2f((ushort)(v[u]>>48));
    }
  }
  for (; j<end; j++){
    float w=cs_w[j];
    unsigned long long v=*(const unsigned long long*)(src+(size_t)cs_col[j]*(4*H));
    a0+=w*b2f((ushort)(v));
    a1+=w*b2f((ushort)(v>>16));
    a2+=w*b2f((ushort)(v>>32));
    a3+=w*b2f((ushort)(v>>48));
  }
  unsigned long long o = (unsigned long long)pack2(a0,a1)
                       | ((unsigned long long)pack2(a2,a3)<<32);
  *(unsigned long long*)(tokens+((size_t)n*4+k+1)*H+sub*4)=o;
}

// ---- one 128x128 @ 128x128^T MFMA step (wave-local 16-row stripe)
__device__ __forceinline__ void pe_gemm(const ushort* Ain, const ushort* __restrict__ W,
                                        const float* __restrict__ bias, ushort* Aout,
                                        bool dorelu, int wid, int l15, int l4){
  bf16x8 a[4];
  #pragma unroll
  for (int kk=0;kk<4;kk++)
    a[kk]=*(const bf16x8*)(Ain + (wid*16+l15)*S1 + kk*32 + l4*8);
  #pragma unroll
  for (int nt=0;nt<8;nt++){
    int n=nt*16+l15;
    f32x4 c={0.f,0.f,0.f,0.f};
    #pragma unroll
    for (int kk=0;kk<4;kk++){
      bf16x8 bb=*(const bf16x8*)(W + (size_t)n*H + kk*32 + l4*8);
      c=__builtin_amdgcn_mfma_f32_16x16x32_bf16(a[kk],bb,c,0,0,0);
    }
    float bv=bias?bias[n]:0.f;
    int rb=wid*16+l4*4;
    #pragma unroll
    for (int reg=0;reg<4;reg++){
      float v=c[reg]+bv;
      if (dorelu) v=fmaxf(v,0.f);
      Aout[(rb+reg)*S1+n]=f2b(v);
    }
  }
}

// ---- PE via MFMA: 128 nodes/block, 8 waves
__global__ __launch_bounds__(512) void pe2_kernel(
    const float* __restrict__ eigvecs, const float* __restrict__ eigvals,
    const float* __restrict__ phi_w1, const float* __restrict__ pe_eps,
    const ushort* __restrict__ wpw2,
    const ushort* __restrict__ wrw1, const float* __restrict__ rho_b1,
    const ushort* __restrict__ wrw2, const float* __restrict__ rho_b2,
    ushort* __restrict__ tokens){
  __shared__ __align__(16) ushort bufA[128*S1];
  __shared__ __align__(16) ushort bufB[128*S1];
  __shared__ float was[H], wbs[H], epss[PP];
  const int tid=threadIdx.x;
  const int wid=tid>>6;
  const int l=tid&63, l15=l&15, l4=(l>>4)&3;
  const int node0=blockIdx.x*128;

  if (tid<H){ was[tid]=phi_w1[tid*2]; wbs[tid]=phi_w1[tid*2+1]; }
  else if (tid<H+PP) epss[tid-H]=pe_eps[tid-H];
  __syncthreads();

  { int rr=tid>>2, seg=tid&3;
    int node=node0+rr; if (node>=NN) node=NN-1;
    float ev[PP], el[PP];
    const float4* evp=(const float4*)(eigvecs+(size_t)node*PP);
    const float4* elp=(const float4*)(eigvals+(size_t)node*PP);
    #pragma unroll
    for (int q=0;q<4;q++){
      float4 a=evp[q], b=elp[q];
      ev[q*4+0]=a.x; ev[q*4+1]=a.y; ev[q*4+2]=a.z; ev[q*4+3]=a.w;
      el[q*4+0]=b.x; el[q*4+1]=b.y; el[q*4+2]=b.z; el[q*4+3]=b.w;
    }
    #pragma unroll
    for (int p=0;p<PP;p++){
      float a=ev[p]; if (isnan(a)) a=0.f;
      float b=el[p]+epss[p]; if (isnan(b)) b=0.f;
      ev[p]=a; el[p]=b;
    }
    for (int j=0;j<32;j++){
      int h=seg*32+j;
      float wa=was[h], wb=wbs[h];
      float acc=0.f;
      #pragma unroll
      for (int p=0;p<PP;p++) acc+=fmaxf(ev[p]*wa+el[p]*wb,0.f);
      bufA[rr*S1+h]=f2b(acc);
    }
  }
  __syncthreads();
  pe_gemm(bufA, wpw2, nullptr, bufB, false, wid, l15, l4);
  __syncthreads();
  pe_gemm(bufB, wrw1, rho_b1, bufA, true, wid, l15, l4);
  __syncthreads();
  { bf16x8 a[4];
    #pragma unroll
    for (int kk=0;kk<4;kk++)
      a[kk]=*(const bf16x8*)(bufA + (wid*16+l15)*S1 + kk*32 + l4*8);
    #pragma unroll
    for (int nt=0;nt<8;nt++){
      int n=nt*16+l15;
      f32x4 c={0.f,0.f,0.f,0.f};
      #pragma unroll
      for (int kk=0;kk<4;kk++){
        bf16x8 bb=*(const bf16x8*)(wrw2 + (size_t)n*H + kk*32 + l4*8);
        c=__builtin_amdgcn_mfma_f32_16x16x32_bf16(a[kk],bb,c,0,0,0);
      }
      float bv=rho_b2[n];
      int rb=wid*16+l4*4;
      #pragma unroll
      for (int reg=0;reg<4;reg++){
        int node=node0+rb+reg;
        if (node<NN){
          size_t idx=(size_t)node*4*H + n;
          tokens[idx]=f2b(b2f(tokens[idx])+c[reg]+bv);
        }
      }
    }
  }
}

// ---- in-register LN for a wave's 16-row stripe; PACKED u32 stores
// (lanes l15 and l15^1 exchange via shfl; even lane writes both halves ->
//  halves store count and avoids same-dword 2x + row-alias 2x bank conflicts)
__device__ __forceinline__ void ln_block(const float (&tk)[8][4], ushort* hb,
                                         const float* g, const float* bta,
                                         int rowb, int l15){
  float gv[8], bv[8];
  #pragma unroll
  for (int nt=0;nt<8;nt++){ gv[nt]=g[nt*16+l15]; bv[nt]=bta[nt*16+l15]; }
  #pragma unroll
  for (int reg=0;reg<4;reg++){
    float s=0.f,q=0.f;
    #pragma unroll
    for (int nt=0;nt<8;nt++){ float v=tk[nt][reg]; s+=v; q+=v*v; }
    #pragma unroll
    for (int m=1;m<16;m<<=1){ s+=__shfl_xor(s,m); q+=__shfl_xor(q,m); }
    float mean=s*(1.f/128.f);
    float rs=rsqrtf(q*(1.f/128.f)-mean*mean+1e-5f);
    int row=rowb+reg;
    #pragma unroll
    for (int nt=0;nt<8;nt++){
      float hv=(tk[nt][reg]-mean)*rs*gv[nt]+bv[nt];
      float ph=__shfl_xor(hv,1);
      if (!(l15&1))
        *(unsigned*)(hb + row*S1 + nt*16+l15)=pack2(hv,ph);
    }
  }
}

// ---- xform9: xform8 + packed-u32 LDS stores (attention-o, FF1)
__global__ __launch_bounds__(512,2) void xform9_kernel(
    const ushort* __restrict__ tokens, const float* __restrict__ hop_emb,
    const ushort* __restrict__ wqkv, const float* __restrict__ qkv_b,
    const ushort* __restrict__ wout, const float* __restrict__ out_b,
    const float* __restrict__ ln1_g, const float* __restrict__ ln1_b,
    const float* __restrict__ ln2_g, const float* __restrict__ ln2_b,
    const ushort* __restrict__ wff1, const float* __restrict__ ff1_b,
    const ushort* __restrict__ wff2, const float* __restrict__ ff2_b,
    const float* __restrict__ fin_g, const float* __restrict__ fin_b,
    const ushort* __restrict__ hw1b, const float* __restrict__ hb1,
    const float* __restrict__ hlng, const float* __restrict__ hlnb,
    const ushort* __restrict__ hw2b, const float* __restrict__ hb2,
    float* __restrict__ out){
  __shared__ __align__(16) ushort hlb[128*S1];   // LN output (A operand)
  __shared__ __align__(16) ushort chA[128*S1];   // attn-o / FF1 chunk
  __shared__ __align__(16) ushort wst[128*S1];   // staged B slice (Wout / Wff2)
  __shared__ float red_s[32*8], red_q[32*8], stat_m[32], stat_r[32];

  const int tid=threadIdx.x;
  const int wid=tid>>6;
  const int l=tid&63, l15=l&15, l4=(l>>4)&3;
  const int node0=blockIdx.x*32;
  const int rowb=wid*16 + l4*4;
  const int rr=tid>>2, seg=tid&3;

  float tokacc[8][4];
  { const ushort* tg=tokens + ((size_t)node0*4 + rowb)*H;
    #pragma unroll
    for (int nt=0;nt<8;nt++){
      int col=nt*16+l15;
      #pragma unroll
      for (int reg=0;reg<4;reg++)
        tokacc[nt][reg]=b2f(tg[reg*H+col]) + hop_emb[reg*H+col];
    }
  }

  for (int ll=0;ll<2;ll++){
    // ---- prefetch Wout + QKV B-fragments (latency hides under LN1 + barrier)
    bf16x8 wreg[4];
    { const ushort* Wl=wout + (size_t)ll*H*H;
      #pragma unroll
      for (int i=0;i<4;i++)
        wreg[i]=*(const bf16x8*)(Wl + (size_t)rr*H + seg*32 + i*8);
    }
    bf16x8 bq[3][4];
    { const ushort* Wl=wqkv + (size_t)ll*384*H;
      #pragma unroll
      for (int j=0;j<3;j++){
        int n=(wid+j*8)*16+l15;
        #pragma unroll
        for (int kk=0;kk<4;kk++)
          bq[j][kk]=*(const bf16x8*)(Wl + (size_t)n*H + kk*32 + l4*8);
      }
    }
    // ---- LN1 -> hlb (bf16, packed)
    ln_block(tokacc, hlb, ln1_g+ll*H, ln1_b+ll*H, rowb, l15);
    __syncthreads();

    // ---- fused QKV GEMM + in-register attention; o -> chA (packed)
    { float bz0=qkv_b[ll*384       + wid*16+l15];
      float bz1=qkv_b[ll*384 + 128 + wid*16+l15];
      float bz2=qkv_b[ll*384 + 256 + wid*16+l15];
      for (int mt=0;mt<8;mt++){
        f32x4 c0={0.f,0.f,0.f,0.f}, c1={0.f,0.f,0.f,0.f}, c2={0.f,0.f,0.f,0.f};
        #pragma unroll
        for (int kk=0;kk<4;kk++){
          bf16x8 a=*(const bf16x8*)(hlb + (mt*16+l15)*S1 + kk*32 + l4*8);
          c0=__builtin_amdgcn_mfma_f32_16x16x32_bf16(a,bq[0][kk],c0,0,0,0);
          c1=__builtin_amdgcn_mfma_f32_16x16x32_bf16(a,bq[1][kk],c1,0,0,0);
          c2=__builtin_amdgcn_mfma_f32_16x16x32_bf16(a,bq[2][kk],c2,0,0,0);
        }
        float qv[4],kv[4],vv[4];
        #pragma unroll
        for (int s=0;s<4;s++){ qv[s]=c0[s]+bz0; kv[s]=c1[s]+bz1; vv[s]=c2[s]+bz2; }
        #pragma unroll
        for (int s=0;s<4;s++){
          float sc[4];
          #pragma unroll
          for (int u=0;u<4;u++){
            float p=qv[s]*kv[u];
            p+=__shfl_xor(p,1); p+=__shfl_xor(p,2);
            p+=__shfl_xor(p,4); p+=__shfl_xor(p,8);
            sc[u]=p*0.25f;
          }
          float m=fmaxf(fmaxf(sc[0],sc[1]),fmaxf(sc[2],sc[3]));
          float e0=__expf(sc[0]-m), e1=__expf(sc[1]-m),
                e2=__expf(sc[2]-m), e3=__expf(sc[3]-m);
          float inv=1.f/(e0+e1+e2+e3);
          float o=(e0*vv[0]+e1*vv[1]+e2*vv[2]+e3*vv[3])*inv;
          float po=__shfl_xor(o,1);
          if (!(l15&1))
            *(unsigned*)(chA + (mt*16+l4*4+s)*S1 + wid*16+l15)=pack2(o,po);
        }
      }
    }
    // ---- write prefetched Wout -> wst
    #pragma unroll
    for (int i=0;i<4;i++)
      *(bf16x8*)(wst + rr*S1 + seg*32 + i*8) = wreg[i];
    __syncthreads();

    // ---- out-proj: tokacc += o @ Wout^T + b (A = chA own stripe, B = wst)
    { bf16x8 aO[4];
      #pragma unroll
      for (int kk=0;kk<4;kk++)
        aO[kk]=*(const bf16x8*)(chA + (wid*16+l15)*S1 + kk*32 + l4*8);
      #pragma unroll
      for (int nt=0;nt<8;nt++){
        int n=nt*16+l15;
        f32x4 c={0.f,0.f,0.f,0.f};
        #pragma unroll
        for (int kk=0;kk<4;kk++){
          bf16x8 bb=*(const bf16x8*)(wst + n*S1 + kk*32 + l4*8);
          c=__builtin_amdgcn_mfma_f32_16x16x32_bf16(aO[kk],bb,c,0,0,0);
        }
        float bias=out_b[ll*H+n];
        #pragma unroll
        for (int reg=0;reg<4;reg++) tokacc[nt][reg]+=c[reg]+bias;
      }
    }

    // ---- prefetch Wff2 chunk 0 + FF1 chunk-0 B (hide under LN2 + barrier)
    const ushort* w2l=wff2 + (size_t)ll*H*512;
    const ushort* w1l=wff1 + (size_t)ll*512*H;
    bf16x8 w2reg[4];
    #pragma unroll
    for (int i=0;i<4;i++)
      w2reg[i]=*(const bf16x8*)(w2l + (size_t)rr*512 + seg*32 + i*8);
    bf16x8 b1reg[4];
    { int n=(0*8+wid)*16+l15;
      #pragma unroll
      for (int kk=0;kk<4;kk++)
        b1reg[kk]=*(const bf16x8*)(w1l + (size_t)n*H + kk*32 + l4*8);
    }

    // ---- LN2 -> hlb (packed)
    ln_block(tokacc, hlb, ln2_g+ll*H, ln2_b+ll*H, rowb, l15);

    // ---- FF: 4 K-chunks; FF1 (B pipelined, packed stores) -> chA; FF2 (B = wst)
    { f32x4 fac[8];
      #pragma unroll
      for (int nt=0;nt<8;nt++) fac[nt]=(f32x4){0.f,0.f,0.f,0.f};
      for (int c0i=0;c0i<4;c0i++){
        __syncthreads();
        #pragma unroll
        for (int i=0;i<4;i++)
          *(bf16x8*)(wst + rr*S1 + seg*32 + i*8) = w2reg[i];
        if (c0i<3){
          #pragma unroll
          for (int i=0;i<4;i++)
            w2reg[i]=*(const bf16x8*)(w2l + (size_t)rr*512 + (c0i+1)*128 + seg*32 + i*8);
        }
        { float bias1=ff1_b[ll*512+(c0i*8+wid)*16+l15];
          for (int mt=0;mt<8;mt++){
            f32x4 c={0.f,0.f,0.f,0.f};
            #pragma unroll
            for (int kk=0;kk<4;kk++){
              bf16x8 a=*(const bf16x8*)(hlb + (mt*16+l15)*S1 + kk*32 + l4*8);
              c=__builtin_amdgcn_mfma_f32_16x16x32_bf16(a,b1reg[kk],c,0,0,0);
            }
            int rb=mt*16+l4*4;
            #pragma unroll
            for (int reg=0;reg<4;reg++){
              float val=fmaxf(c[reg]+bias1,0.f);
              float pv=__shfl_xor(val,1);
              if (!(l15&1))
                *(unsigned*)(chA + (rb+reg)*S1 + wid*16+l15)=pack2(val,pv);
            }
          }
        }
        if (c0i<3){
          int n2=((c0i+1)*8+wid)*16+l15;
          #pragma unroll
          for (int kk=0;kk<4;kk++)
            b1reg[kk]=*(const bf16x8*)(w1l + (size_t)n2*H + kk*32 + l4*8);
        }
        __syncthreads();
        { bf16x8 a2[4];
          #pragma unroll
          for (int kk=0;kk<4;kk++)
            a2[kk]=*(const bf16x8*)(chA + (wid*16+l15)*S1 + kk*32 + l4*8);
          #pragma unroll
          for (int nt=0;nt<8;nt++){
            int n2=nt*16+l15;
            #pragma unroll
            for (int kk=0;kk<4;kk++){
              bf16x8 bb=*(const bf16x8*)(wst + n2*S1 + kk*32 + l4*8);
              fac[nt]=__builtin_amdgcn_mfma_f32_16x16x32_bf16(a2[kk],bb,fac[nt],0,0,0);
            }
          }
        }
      }
      #pragma unroll
      for (int nt=0;nt<8;nt++){
        float b2v=ff2_b[ll*H + nt*16+l15];
        #pragma unroll
        for (int reg=0;reg<4;reg++) tokacc[nt][reg]+=fac[nt][reg]+b2v;
      }
    }
    __syncthreads();
  }

  // ---- final LN on token-0 rows (reg==0), compact to hlb rows 0..31 (packed)
  { float s=0.f,q=0.f;
    #pragma unroll
    for (int nt=0;nt<8;nt++){ float v=tokacc[nt][0]; s+=v; q+=v*v; }
    #pragma unroll
    for (int m=1;m<16;m<<=1){ s+=__shfl_xor(s,m); q+=__shfl_xor(q,m); }
    float mean=s*(1.f/128.f);
    float rs=rsqrtf(q*(1.f/128.f)-mean*mean+1e-5f);
    int ci=wid*4+l4;
    #pragma unroll
    for (int nt=0;nt<8;nt++){
      int col=nt*16+l15;
      float hv=(tokacc[nt][0]-mean)*rs*fin_g[col]+fin_b[col];
      float ph=__shfl_xor(hv,1);
      if (!(l15&1))
        *(unsigned*)(hlb + ci*S1 + col)=pack2(hv,ph);
    }
  }
  __syncthreads();

  // ---- head GEMM1 [32x128]@hw1^T + gelu
  float gel[2][4];
  { int n=wid*16+l15;
    bf16x8 bh[4];
    #pragma unroll
    for (int kk=0;kk<4;kk++)
      bh[kk]=*(const bf16x8*)(hw1b + (size_t)n*H + kk*32 + l4*8);
    float hb1v=hb1[n];
    #pragma unroll
    for (int mt=0;mt<2;mt++){
      f32x4 c={0.f,0.f,0.f,0.f};
      #pragma unroll
      for (int kk=0;kk<4;kk++){
        bf16x8 a=*(const bf16x8*)(hlb + (mt*16+l15)*S1 + kk*32 + l4*8);
        c=__builtin_amdgcn_mfma_f32_16x16x32_bf16(a,bh[kk],c,0,0,0);
      }
      #pragma unroll
      for (int reg=0;reg<4;reg++){
        float xx=c[reg]+hb1v;
        gel[mt][reg]=0.5f*xx*(1.f+erff(xx*0.70710678118654752f));
      }
    }
  }
  // ---- head LN (cross-wave)
  #pragma unroll
  for (int mt=0;mt<2;mt++){
    #pragma unroll
    for (int reg=0;reg<4;reg++){
      float v=gel[mt][reg], sv=v, qv=v*v;
      #pragma unroll
      for (int m=1;m<16;m<<=1){ sv+=__shfl_xor(sv,m); qv+=__shfl_xor(qv,m); }
      if (l15==0){ int r32=mt*16+l4*4+reg; red_s[r32*8+wid]=sv; red_q[r32*8+wid]=qv; }
    }
  }
  __syncthreads();
  if (tid<32){
    float ss=0.f,qs=0.f;
    #pragma unroll
    for (int w=0;w<8;w++){ ss+=red_s[tid*8+w]; qs+=red_q[tid*8+w]; }
    float mm=ss*(1.f/128.f);
    stat_m[tid]=mm;
    stat_r[tid]=rsqrtf(qs*(1.f/128.f)-mm*mm+1e-5f);
  }
  __syncthreads();
  { int n=wid*16+l15;
    float hg=hlng[n], hbv=hlnb[n];
    #pragma unroll
    for (int mt=0;mt<2;mt++){
      #pragma unroll
      for (int reg=0;reg<4;reg++){
        int r32=mt*16+l4*4+reg;
        float z=(gel[mt][reg]-stat_m[r32])*stat_r[r32]*hg+hbv;
        hlb[r32*S1+n]=f2b(z);
      }
    }
  }
  __syncthreads();

  // ---- head GEMM2 [32x128] @ hw2^T -> out (waves 0,1)
  if (wid<2){
    int mt=wid;
    bool valid=l15<10;
    bf16x8 b2[4];
    #pragma unroll
    for (int kk=0;kk<4;kk++){
      if (valid) b2[kk]=*(const bf16x8*)(hw2b + (size_t)l15*H + kk*32 + l4*8);
      else { bf16x8 z; for (int t=0;t<8;t++) z[t]=0; b2[kk]=z; }
    }
    f32x4 c={0.f,0.f,0.f,0.f};
    #pragma unroll
    for (int kk=0;kk<4;kk++){
      bf16x8 av=*(const bf16x8*)(hlb + (mt*16+l15)*S1 + kk*32 + l4*8);
      c=__builtin_amdgcn_mfma_f32_16x16x32_bf16(av,b2[kk],c,0,0,0);
    }
    if (valid){
      float bb2=hb2[l15];
      #pragma unroll
      for (int reg=0;reg<4;reg++){
        int i=mt*16+l4*4+reg;
        out[((size_t)node0+i)*10 + l15]=c[reg]+bb2;
      }
    }
  }
}

extern "C" void kernel_launch(void* const* d_in, const int* in_sizes, int n_in,
                              void* d_out, int out_size, void* d_ws, size_t ws_size,
                              hipStream_t stream){
  const float* x       =(const float*)d_in[0];
  const int*   ei      =(const int*)  d_in[1];
  const float* eigvecs =(const float*)d_in[2];
  const float* eigvals =(const float*)d_in[3];
  const float* enc_w   =(const float*)d_in[4];
  const float* enc_b   =(const float*)d_in[5];
  const float* in_ln_g =(const float*)d_in[6];
  const float* in_ln_b =(const float*)d_in[7];
  const float* pe_phi_w1=(const float*)d_in[8];
  const float* pe_phi_w2=(const float*)d_in[9];
  const float* pe_rho_w1=(const float*)d_in[10];
  const float* pe_rho_b1=(const float*)d_in[11];
  const float* pe_rho_w2=(const float*)d_in[12];
  const float* pe_rho_b2=(const float*)d_in[13];
  const float* pe_eps  =(const float*)d_in[14];
  const float* hop_emb =(const float*)d_in[15];
  const float* qkv_w   =(const float*)d_in[16];
  const float* qkv_b   =(const float*)d_in[17];
  const float* out_w   =(const float*)d_in[18];
  const float* out_b   =(const float*)d_in[19];
  const float* ln1_g   =(const float*)d_in[20];
  const float* ln1_b   =(const float*)d_in[21];
  const float* ln2_g   =(const float*)d_in[22];
  const float* ln2_b   =(const float*)d_in[23];
  const float* ff1_w   =(const float*)d_in[24];
  const float* ff1_b   =(const float*)d_in[25];
  const float* ff2_w   =(const float*)d_in[26];
  const float* ff2_b   =(const float*)d_in[27];
  const float* fin_g   =(const float*)d_in[28];
  const float* fin_b   =(const float*)d_in[29];
  const float* hw1     =(const float*)d_in[30];
  const float* hb1     =(const float*)d_in[31];
  const float* hlg     =(const float*)d_in[32];
  const float* hlb_    =(const float*)d_in[33];
  const float* hw2     =(const float*)d_in[34];
  const float* hb2     =(const float*)d_in[35];

  char* ws=(char*)d_ws;
  size_t off=0;
  auto alloc=[&](size_t bytes)->void*{
    void* p=ws+off;
    off+=(bytes+255)&~(size_t)255;
    return p;
  };
  ushort* tokens=(ushort*)alloc((size_t)NN*4*H*sizeof(ushort));  // 102.4 MB bf16
  float* deg    =(float*)alloc((size_t)NN*sizeof(float));
  int*   counts =(int*)  alloc((size_t)NN*sizeof(int));
  int*   row_ptr=(int*)  alloc((size_t)(NN+1)*sizeof(int));
  int*   cursor =(int*)  alloc((size_t)NN*sizeof(int));
  int*   cs_col =(int*)  alloc((size_t)EE*sizeof(int));
  float* cs_w   =(float*)alloc((size_t)EE*sizeof(float));
  int*   flag   =(int*)  alloc(256);
  int*   bsum   =(int*)  alloc(64*sizeof(int));
  ushort* wqkvb =(ushort*)alloc((size_t)2*384*H*sizeof(ushort));
  ushort* woutb =(ushort*)alloc((size_t)2*H*H*sizeof(ushort));
  ushort* wff1b =(ushort*)alloc((size_t)2*512*H*sizeof(ushort));
  ushort* wff2b =(ushort*)alloc((size_t)2*H*512*sizeof(ushort));
  ushort* hw1b  =(ushort*)alloc((size_t)H*H*sizeof(ushort));
  ushort* hw2b  =(ushort*)alloc((size_t)10*H*sizeof(ushort));
  ushort* wpw2b =(ushort*)alloc((size_t)H*H*sizeof(ushort));
  ushort* wrw1b =(ushort*)alloc((size_t)H*H*sizeof(ushort));
  ushort* wrw2b =(ushort*)alloc((size_t)H*H*sizeof(ushort));
  ushort* wencb =(ushort*)alloc((size_t)H*H*sizeof(ushort));
  if (off>ws_size) return;

  const int NB=(NN+SCB-1)/SCB;   // 25 scan blocks

  hipMemsetAsync(deg,0,(size_t)NN*sizeof(float),stream);
  hipMemsetAsync(counts,0,(size_t)NN*sizeof(int),stream);
  detect_kernel<<<1,256,0,stream>>>(ei,flag);

  // single fused weight-conversion launch
  CvtArgs ca;
  const float* srcs[10]={qkv_w,out_w,ff1_w,ff2_w,hw1,hw2,pe_phi_w2,pe_rho_w1,pe_rho_w2,enc_w};
  ushort* dsts[10]={wqkvb,woutb,wff1b,wff2b,hw1b,hw2b,wpw2b,wrw1b,wrw2b,wencb};
  int ns[10]={2*384*H,2*H*H,2*512*H,2*H*512,H*H,10*H,H*H,H*H,H*H,H*H};
  int acc=0;
  for (int i=0;i<10;i++){ ca.src[i]=srcs[i]; ca.dst[i]=dsts[i]; ca.off[i]=acc; acc+=ns[i]; }
  ca.off[10]=acc;
  cvtall_kernel<<<(acc+255)/256,256,0,stream>>>(ca);

  enc2_kernel<<<(NN+127)/128,512,0,stream>>>(x,wencb,enc_b,in_ln_g,in_ln_b,tokens);
  hist_kernel<<<(EE+255)/256,256,0,stream>>>(ei,flag,deg,counts);
  dinv_kernel<<<(NN+255)/256,256,0,stream>>>(deg);
  scanp1_kernel<<<NB,1024,0,stream>>>(counts,bsum);
  scanp2_kernel<<<1,64,0,stream>>>(bsum,NB,row_ptr);
  scanp3_kernel<<<NB,1024,0,stream>>>(counts,bsum,row_ptr,cursor);
  scatter_kernel<<<(EE+255)/256,256,0,stream>>>(ei,flag,cursor,deg,cs_col,cs_w);
  for (int k=0;k<3;k++)
    spmm2_kernel<<<NN/8,256,0,stream>>>(tokens,row_ptr,cs_col,cs_w,k);
  pe2_kernel<<<(NN+127)/128,512,0,stream>>>(eigvecs,eigvals,pe_phi_w1,pe_eps,
                                            wpw2b,wrw1b,pe_rho_b1,wrw2b,pe_rho_b2,
                                            tokens);
  xform9_kernel<<<NN/32,512,0,stream>>>(tokens,hop_emb,
                                        wqkvb,qkv_b,woutb,out_b,
                                        ln1_g,ln1_b,ln2_g,ln2_b,
                                        wff1b,ff1_b,wff2b,ff2_b,
                                        fin_g,fin_b,hw1b,hb1,hlg,hlb_,hw2b,hb2,
                                        (float*)d_out);
}

// Round 15
// 1556.149 us; speedup vs baseline: 1.2100x; 1.2100x over previous
//
#include <hip/hip_runtime.h>
#include <cmath>

#define NN 100000
#define EE 1600000
#define H 128
#define PP 16
#define S1 136   // LDS A-stride (halfwords)
#define SCB 4096 // scan elements per block

typedef __attribute__((ext_vector_type(8))) short bf16x8;
typedef __attribute__((ext_vector_type(4))) float f32x4;

__device__ __forceinline__ ushort f2b(float f){
  union{float f; unsigned u;} x; x.f=f;
  unsigned r=(x.u + 0x7fffu + ((x.u>>16)&1u))>>16;
  return (ushort)r;
}
__device__ __forceinline__ float b2f(ushort h){
  union{unsigned u; float f;} x; x.u=((unsigned)h)<<16; return x.f;
}
__device__ __forceinline__ unsigned pack2(float a, float b){
  return (unsigned)f2b(a) | ((unsigned)f2b(b)<<16);
}

// ---- fused weight fp32->bf16 conversion (single launch, 10 segments)
struct CvtArgs {
  const float* src[10];
  ushort* dst[10];
  int off[11];
};
__global__ void cvtall_kernel(CvtArgs a){
  int i=blockIdx.x*256+threadIdx.x;
  if (i>=a.off[10]) return;
  int s=0;
  #pragma unroll
  for (int k=1;k<10;k++) if (i>=a.off[k]) s=k;
  int local=i-a.off[s];
  a.dst[s][local]=f2b(a.src[s][local]);
}

// ---- edge_index dtype detect: flag=1 if int64 (odd words all zero), else 0
__global__ void detect_kernel(const int* __restrict__ ei, int* __restrict__ flag){
  __shared__ int nz;
  if (threadIdx.x==0) nz=0;
  __syncthreads();
  for (int i=threadIdx.x; i<2048; i+=256){
    if (ei[2*i+1]!=0) nz=1;
  }
  __syncthreads();
  if (threadIdx.x==0) flag[0] = nz ? 0 : 1;
}

// ---- MFMA encoder: tokens[n,0,:] = LN(x @ enc_w^T + enc_b); 128 nodes/block
__global__ __launch_bounds__(512) void enc2_kernel(
    const float* __restrict__ x, const ushort* __restrict__ wenc,
    const float* __restrict__ enc_b,
    const float* __restrict__ g, const float* __restrict__ bb,
    ushort* __restrict__ tokens){
  __shared__ __align__(16) ushort bufA[128*S1];
  const int tid=threadIdx.x;
  const int wid=tid>>6;
  const int l=tid&63, l15=l&15, l4=(l>>4)&3;
  const int node0=blockIdx.x*128;
  const int rowb=wid*16 + l4*4;

  { int rr=tid>>2, seg=tid&3;
    int node=node0+rr; if (node>=NN) node=NN-1;
    const float4* xr=(const float4*)(x+(size_t)node*H+seg*32);
    #pragma unroll
    for (int i=0;i<8;i++){
      float4 v=xr[i];
      *(unsigned*)(bufA + rr*S1 + seg*32 + i*4)   = pack2(v.x,v.y);
      *(unsigned*)(bufA + rr*S1 + seg*32 + i*4+2) = pack2(v.z,v.w);
    }
  }
  __syncthreads();

  bf16x8 a[4];
  #pragma unroll
  for (int kk=0;kk<4;kk++)
    a[kk]=*(const bf16x8*)(bufA + (wid*16+l15)*S1 + kk*32 + l4*8);
  float acc[8][4];
  #pragma unroll
  for (int nt=0;nt<8;nt++){
    int n=nt*16+l15;
    f32x4 c={0.f,0.f,0.f,0.f};
    #pragma unroll
    for (int kk=0;kk<4;kk++){
      bf16x8 bbf=*(const bf16x8*)(wenc + (size_t)n*H + kk*32 + l4*8);
      c=__builtin_amdgcn_mfma_f32_16x16x32_bf16(a[kk],bbf,c,0,0,0);
    }
    float bv=enc_b[n];
    #pragma unroll
    for (int reg=0;reg<4;reg++) acc[nt][reg]=c[reg]+bv;
  }
  float gv[8], bvv[8];
  #pragma unroll
  for (int nt=0;nt<8;nt++){ gv[nt]=g[nt*16+l15]; bvv[nt]=bb[nt*16+l15]; }
  #pragma unroll
  for (int reg=0;reg<4;reg++){
    float s=0.f,q=0.f;
    #pragma unroll
    for (int nt=0;nt<8;nt++){ float v=acc[nt][reg]; s+=v; q+=v*v; }
    #pragma unroll
    for (int m=1;m<16;m<<=1){ s+=__shfl_xor(s,m); q+=__shfl_xor(q,m); }
    float mean=s*(1.f/128.f);
    float rs=rsqrtf(q*(1.f/128.f)-mean*mean+1e-5f);
    int node=node0+rowb+reg;
    if (node<NN){
      #pragma unroll
      for (int nt=0;nt<8;nt++)
        tokens[(size_t)node*4*H + nt*16+l15]=f2b((acc[nt][reg]-mean)*rs*gv[nt]+bvv[nt]);
    }
  }
}

// ---- histograms
__global__ void hist_kernel(const int* __restrict__ ei, const int* __restrict__ flag,
                            float* __restrict__ deg, int* __restrict__ counts){
  int f=flag[0];
  int e=blockIdx.x*256+threadIdx.x;
  if (e>=EE) return;
  int rw=ei[(size_t)e<<f];
  int cl=ei[((size_t)EE+e)<<f];
  atomicAdd(&counts[rw],1);
  atomicAdd(&deg[cl],1.0f);
}

__global__ void dinv_kernel(float* __restrict__ deg){
  int i=blockIdx.x*256+threadIdx.x;
  if (i<NN) deg[i]=rsqrtf(fmaxf(deg[i],1.0f));
}

// ---- multi-block scan: phase 1 = per-block sums
__global__ __launch_bounds__(1024) void scanp1_kernel(const int* __restrict__ counts,
                                                      int* __restrict__ bsum){
  int b=blockIdx.x, tid=threadIdx.x;
  int base=b*SCB;
  int s=0;
  for (int i=tid;i<SCB;i+=1024){
    int idx=base+i;
    s += (idx<NN)?counts[idx]:0;
  }
  s+=__shfl_xor(s,32); s+=__shfl_xor(s,16); s+=__shfl_xor(s,8);
  s+=__shfl_xor(s,4);  s+=__shfl_xor(s,2);  s+=__shfl_xor(s,1);
  __shared__ int ws[16];
  if ((tid&63)==0) ws[tid>>6]=s;
  __syncthreads();
  if (tid==0){
    int t=0;
    #pragma unroll
    for (int w=0;w<16;w++) t+=ws[w];
    bsum[b]=t;
  }
}
// ---- phase 2: serial exclusive scan of block sums (tiny) + total -> row_ptr[NN]
__global__ void scanp2_kernel(int* __restrict__ bsum, int nb, int* __restrict__ row_ptr){
  if (threadIdx.x==0 && blockIdx.x==0){
    int acc=0;
    for (int i=0;i<nb;i++){ int v=bsum[i]; bsum[i]=acc; acc+=v; }
    bsum[nb]=acc;
    row_ptr[NN]=acc;
  }
}
// ---- phase 3: per-block exclusive scan + offset -> row_ptr, cursor
__global__ __launch_bounds__(1024) void scanp3_kernel(const int* __restrict__ counts,
                                                      const int* __restrict__ bsum,
                                                      int* __restrict__ row_ptr,
                                                      int* __restrict__ cursor){
  int b=blockIdx.x;
  int tid=threadIdx.x, lane=tid&63, w=tid>>6;
  __shared__ int ws[16];
  __shared__ int carry_s;
  if (tid==0) carry_s=bsum[b];
  __syncthreads();
  int base=b*SCB;
  for (int it=0; it<SCB; it+=1024){
    int i=base+it+tid;
    int v=(i<NN)?counts[i]:0;
    int x=v;
    for (int off=1; off<64; off<<=1){
      int t=__shfl_up(x,off);
      if (lane>=off) x+=t;
    }
    if (lane==63) ws[w]=x;
    __syncthreads();
    int woff=0;
    #pragma unroll
    for (int ww=0; ww<16; ww++) if (ww<w) woff+=ws[ww];
    int carry=carry_s;
    int excl=carry+woff+x-v;
    if (i<NN){ row_ptr[i]=excl; cursor[i]=excl; }
    __syncthreads();
    if (tid==1023) carry_s = carry + woff + x;
    __syncthreads();
  }
}

// ---- scatter edges into CSR
__global__ void scatter_kernel(const int* __restrict__ ei, const int* __restrict__ flag,
                               int* __restrict__ cursor, const float* __restrict__ dinv,
                               int* __restrict__ cs_col, float* __restrict__ cs_w){
  int f=flag[0];
  int e=blockIdx.x*256+threadIdx.x;
  if (e>=EE) return;
  int rw=ei[(size_t)e<<f];
  int cl=ei[((size_t)EE+e)<<f];
  int pos=atomicAdd(&cursor[rw],1);
  cs_col[pos]=cl;
  cs_w[pos]=dinv[rw]*dinv[cl];
}

// ---- SpMM hop v2: 32 lanes per node, 8B per lane; 8 nodes/block
__global__ __launch_bounds__(256) void spmm2_kernel(ushort* __restrict__ tokens,
    const int* __restrict__ row_ptr, const int* __restrict__ cs_col,
    const float* __restrict__ cs_w, int k){
  int tid=threadIdx.x;
  int nl=tid>>5;
  int sub=tid&31;
  int n=blockIdx.x*8+nl;
  int beg=row_ptr[n], end=row_ptr[n+1];
  float a0=0.f,a1=0.f,a2=0.f,a3=0.f;
  const ushort* src=tokens+(size_t)k*H+sub*4;
  int j=beg;
  for (; j+8<=end; j+=8){
    int   c[8]; float w[8]; unsigned long long v[8];
    #pragma unroll
    for (int u=0;u<8;u++){ c[u]=cs_col[j+u]; w[u]=cs_w[j+u]; }
    #pragma unroll
    for (int u=0;u<8;u++) v[u]=*(const unsigned long long*)(src+(size_t)c[u]*(4*H));
    #pragma unroll
    for (int u=0;u<8;u++){
      a0+=w[u]*b2f((ushort)(v[u]));
      a1+=w[u]*b2f((ushort)(v[u]>>16));
      a2+=w[u]*b2f((ushort)(v[u]>>32));
      a3+=w[u]*b2f((ushort)(v[u]>>48));
    }
  }
  for (; j<end; j++){
    float w=cs_w[j];
    unsigned long long v=*(const unsigned long long*)(src+(size_t)cs_col[j]*(4*H));
    a0+=w*b2f((ushort)(v));
    a1+=w*b2f((ushort)(v>>16));
    a2+=w*b2f((ushort)(v>>32));
    a3+=w*b2f((ushort)(v>>48));
  }
  unsigned long long o = (unsigned long long)pack2(a0,a1)
                       | ((unsigned long long)pack2(a2,a3)<<32);
  *(unsigned long long*)(tokens+((size_t)n*4+k+1)*H+sub*4)=o;
}

// ---- one 128x128 @ 128x128^T MFMA step (wave-local 16-row stripe)
__device__ __forceinline__ void pe_gemm(const ushort* Ain, const ushort* __restrict__ W,
                                        const float* __restrict__ bias, ushort* Aout,
                                        bool dorelu, int wid, int l15, int l4){
  bf16x8 a[4];
  #pragma unroll
  for (int kk=0;kk<4;kk++)
    a[kk]=*(const bf16x8*)(Ain + (wid*16+l15)*S1 + kk*32 + l4*8);
  #pragma unroll
  for (int nt=0;nt<8;nt++){
    int n=nt*16+l15;
    f32x4 c={0.f,0.f,0.f,0.f};
    #pragma unroll
    for (int kk=0;kk<4;kk++){
      bf16x8 bb=*(const bf16x8*)(W + (size_t)n*H + kk*32 + l4*8);
      c=__builtin_amdgcn_mfma_f32_16x16x32_bf16(a[kk],bb,c,0,0,0);
    }
    float bv=bias?bias[n]:0.f;
    int rb=wid*16+l4*4;
    #pragma unroll
    for (int reg=0;reg<4;reg++){
      float v=c[reg]+bv;
      if (dorelu) v=fmaxf(v,0.f);
      Aout[(rb+reg)*S1+n]=f2b(v);
    }
  }
}

// ---- PE via MFMA: 128 nodes/block, 8 waves
__global__ __launch_bounds__(512) void pe2_kernel(
    const float* __restrict__ eigvecs, const float* __restrict__ eigvals,
    const float* __restrict__ phi_w1, const float* __restrict__ pe_eps,
    const ushort* __restrict__ wpw2,
    const ushort* __restrict__ wrw1, const float* __restrict__ rho_b1,
    const ushort* __restrict__ wrw2, const float* __restrict__ rho_b2,
    ushort* __restrict__ tokens){
  __shared__ __align__(16) ushort bufA[128*S1];
  __shared__ __align__(16) ushort bufB[128*S1];
  __shared__ float was[H], wbs[H], epss[PP];
  const int tid=threadIdx.x;
  const int wid=tid>>6;
  const int l=tid&63, l15=l&15, l4=(l>>4)&3;
  const int node0=blockIdx.x*128;

  if (tid<H){ was[tid]=phi_w1[tid*2]; wbs[tid]=phi_w1[tid*2+1]; }
  else if (tid<H+PP) epss[tid-H]=pe_eps[tid-H];
  __syncthreads();

  { int rr=tid>>2, seg=tid&3;
    int node=node0+rr; if (node>=NN) node=NN-1;
    float ev[PP], el[PP];
    const float4* evp=(const float4*)(eigvecs+(size_t)node*PP);
    const float4* elp=(const float4*)(eigvals+(size_t)node*PP);
    #pragma unroll
    for (int q=0;q<4;q++){
      float4 a=evp[q], b=elp[q];
      ev[q*4+0]=a.x; ev[q*4+1]=a.y; ev[q*4+2]=a.z; ev[q*4+3]=a.w;
      el[q*4+0]=b.x; el[q*4+1]=b.y; el[q*4+2]=b.z; el[q*4+3]=b.w;
    }
    #pragma unroll
    for (int p=0;p<PP;p++){
      float a=ev[p]; if (isnan(a)) a=0.f;
      float b=el[p]+epss[p]; if (isnan(b)) b=0.f;
      ev[p]=a; el[p]=b;
    }
    for (int j=0;j<32;j++){
      int h=seg*32+j;
      float wa=was[h], wb=wbs[h];
      float acc=0.f;
      #pragma unroll
      for (int p=0;p<PP;p++) acc+=fmaxf(ev[p]*wa+el[p]*wb,0.f);
      bufA[rr*S1+h]=f2b(acc);
    }
  }
  __syncthreads();
  pe_gemm(bufA, wpw2, nullptr, bufB, false, wid, l15, l4);
  __syncthreads();
  pe_gemm(bufB, wrw1, rho_b1, bufA, true, wid, l15, l4);
  __syncthreads();
  { bf16x8 a[4];
    #pragma unroll
    for (int kk=0;kk<4;kk++)
      a[kk]=*(const bf16x8*)(bufA + (wid*16+l15)*S1 + kk*32 + l4*8);
    #pragma unroll
    for (int nt=0;nt<8;nt++){
      int n=nt*16+l15;
      f32x4 c={0.f,0.f,0.f,0.f};
      #pragma unroll
      for (int kk=0;kk<4;kk++){
        bf16x8 bb=*(const bf16x8*)(wrw2 + (size_t)n*H + kk*32 + l4*8);
        c=__builtin_amdgcn_mfma_f32_16x16x32_bf16(a[kk],bb,c,0,0,0);
      }
      float bv=rho_b2[n];
      int rb=wid*16+l4*4;
      #pragma unroll
      for (int reg=0;reg<4;reg++){
        int node=node0+rb+reg;
        if (node<NN){
          size_t idx=(size_t)node*4*H + n;
          tokens[idx]=f2b(b2f(tokens[idx])+c[reg]+bv);
        }
      }
    }
  }
}

// ---- in-register LN for a wave's 16-row stripe
__device__ __forceinline__ void ln_block(const float (&tk)[8][4], ushort* hb,
                                         const float* g, const float* bta,
                                         int rowb, int l15){
  float gv[8], bv[8];
  #pragma unroll
  for (int nt=0;nt<8;nt++){ gv[nt]=g[nt*16+l15]; bv[nt]=bta[nt*16+l15]; }
  #pragma unroll
  for (int reg=0;reg<4;reg++){
    float s=0.f,q=0.f;
    #pragma unroll
    for (int nt=0;nt<8;nt++){ float v=tk[nt][reg]; s+=v; q+=v*v; }
    #pragma unroll
    for (int m=1;m<16;m<<=1){ s+=__shfl_xor(s,m); q+=__shfl_xor(q,m); }
    float mean=s*(1.f/128.f);
    float rs=rsqrtf(q*(1.f/128.f)-mean*mean+1e-5f);
    int row=rowb+reg;
    #pragma unroll
    for (int nt=0;nt<8;nt++){
      float hv=(tk[nt][reg]-mean)*rs*gv[nt]+bv[nt];
      hb[row*S1 + nt*16+l15]=f2b(hv);
    }
  }
}

// ---- xform8: 32 nodes, 8 waves, staged-B + async prefetch (best structure)
__global__ __launch_bounds__(512,2) void xform8_kernel(
    const ushort* __restrict__ tokens, const float* __restrict__ hop_emb,
    const ushort* __restrict__ wqkv, const float* __restrict__ qkv_b,
    const ushort* __restrict__ wout, const float* __restrict__ out_b,
    const float* __restrict__ ln1_g, const float* __restrict__ ln1_b,
    const float* __restrict__ ln2_g, const float* __restrict__ ln2_b,
    const ushort* __restrict__ wff1, const float* __restrict__ ff1_b,
    const ushort* __restrict__ wff2, const float* __restrict__ ff2_b,
    const float* __restrict__ fin_g, const float* __restrict__ fin_b,
    const ushort* __restrict__ hw1b, const float* __restrict__ hb1,
    const float* __restrict__ hlng, const float* __restrict__ hlnb,
    const ushort* __restrict__ hw2b, const float* __restrict__ hb2,
    float* __restrict__ out){
  __shared__ __align__(16) ushort hlb[128*S1];   // LN output (A operand)
  __shared__ __align__(16) ushort chA[128*S1];   // attn-o / FF1 chunk
  __shared__ __align__(16) ushort wst[128*S1];   // staged B slice (Wout / Wff2)
  __shared__ float red_s[32*8], red_q[32*8], stat_m[32], stat_r[32];

  const int tid=threadIdx.x;
  const int wid=tid>>6;
  const int l=tid&63, l15=l&15, l4=(l>>4)&3;
  const int node0=blockIdx.x*32;
  const int rowb=wid*16 + l4*4;
  const int rr=tid>>2, seg=tid&3;

  float tokacc[8][4];
  { const ushort* tg=tokens + ((size_t)node0*4 + rowb)*H;
    #pragma unroll
    for (int nt=0;nt<8;nt++){
      int col=nt*16+l15;
      #pragma unroll
      for (int reg=0;reg<4;reg++)
        tokacc[nt][reg]=b2f(tg[reg*H+col]) + hop_emb[reg*H+col];
    }
  }

  for (int ll=0;ll<2;ll++){
    // ---- prefetch Wout + QKV B-fragments (latency hides under LN1 + barrier)
    bf16x8 wreg[4];
    { const ushort* Wl=wout + (size_t)ll*H*H;
      #pragma unroll
      for (int i=0;i<4;i++)
        wreg[i]=*(const bf16x8*)(Wl + (size_t)rr*H + seg*32 + i*8);
    }
    bf16x8 bq[3][4];
    { const ushort* Wl=wqkv + (size_t)ll*384*H;
      #pragma unroll
      for (int j=0;j<3;j++){
        int n=(wid+j*8)*16+l15;
        #pragma unroll
        for (int kk=0;kk<4;kk++)
          bq[j][kk]=*(const bf16x8*)(Wl + (size_t)n*H + kk*32 + l4*8);
      }
    }
    // ---- LN1 -> hlb (bf16)
    ln_block(tokacc, hlb, ln1_g+ll*H, ln1_b+ll*H, rowb, l15);
    __syncthreads();

    // ---- fused QKV GEMM + in-register attention; o -> chA
    { float bz0=qkv_b[ll*384       + wid*16+l15];
      float bz1=qkv_b[ll*384 + 128 + wid*16+l15];
      float bz2=qkv_b[ll*384 + 256 + wid*16+l15];
      for (int mt=0;mt<8;mt++){
        f32x4 c0={0.f,0.f,0.f,0.f}, c1={0.f,0.f,0.f,0.f}, c2={0.f,0.f,0.f,0.f};
        #pragma unroll
        for (int kk=0;kk<4;kk++){
          bf16x8 a=*(const bf16x8*)(hlb + (mt*16+l15)*S1 + kk*32 + l4*8);
          c0=__builtin_amdgcn_mfma_f32_16x16x32_bf16(a,bq[0][kk],c0,0,0,0);
          c1=__builtin_amdgcn_mfma_f32_16x16x32_bf16(a,bq[1][kk],c1,0,0,0);
          c2=__builtin_amdgcn_mfma_f32_16x16x32_bf16(a,bq[2][kk],c2,0,0,0);
        }
        float qv[4],kv[4],vv[4];
        #pragma unroll
        for (int s=0;s<4;s++){ qv[s]=c0[s]+bz0; kv[s]=c1[s]+bz1; vv[s]=c2[s]+bz2; }
        #pragma unroll
        for (int s=0;s<4;s++){
          float sc[4];
          #pragma unroll
          for (int u=0;u<4;u++){
            float p=qv[s]*kv[u];
            p+=__shfl_xor(p,1); p+=__shfl_xor(p,2);
            p+=__shfl_xor(p,4); p+=__shfl_xor(p,8);
            sc[u]=p*0.25f;
          }
          float m=fmaxf(fmaxf(sc[0],sc[1]),fmaxf(sc[2],sc[3]));
          float e0=__expf(sc[0]-m), e1=__expf(sc[1]-m),
                e2=__expf(sc[2]-m), e3=__expf(sc[3]-m);
          float inv=1.f/(e0+e1+e2+e3);
          float o=(e0*vv[0]+e1*vv[1]+e2*vv[2]+e3*vv[3])*inv;
          chA[(mt*16+l4*4+s)*S1 + wid*16+l15]=f2b(o);
        }
      }
    }
    // ---- write prefetched Wout -> wst (loads long since complete)
    #pragma unroll
    for (int i=0;i<4;i++)
      *(bf16x8*)(wst + rr*S1 + seg*32 + i*8) = wreg[i];
    __syncthreads();

    // ---- out-proj: tokacc += o @ Wout^T + b (A = chA own stripe, B = wst)
    { bf16x8 aO[4];
      #pragma unroll
      for (int kk=0;kk<4;kk++)
        aO[kk]=*(const bf16x8*)(chA + (wid*16+l15)*S1 + kk*32 + l4*8);
      #pragma unroll
      for (int nt=0;nt<8;nt++){
        int n=nt*16+l15;
        f32x4 c={0.f,0.f,0.f,0.f};
        #pragma unroll
        for (int kk=0;kk<4;kk++){
          bf16x8 bb=*(const bf16x8*)(wst + n*S1 + kk*32 + l4*8);
          c=__builtin_amdgcn_mfma_f32_16x16x32_bf16(aO[kk],bb,c,0,0,0);
        }
        float bias=out_b[ll*H+n];
        #pragma unroll
        for (int reg=0;reg<4;reg++) tokacc[nt][reg]+=c[reg]+bias;
      }
    }

    // ---- prefetch Wff2 chunk 0 + FF1 chunk-0 B (hide under LN2 + barrier)
    const ushort* w2l=wff2 + (size_t)ll*H*512;
    const ushort* w1l=wff1 + (size_t)ll*512*H;
    bf16x8 w2reg[4];
    #pragma unroll
    for (int i=0;i<4;i++)
      w2reg[i]=*(const bf16x8*)(w2l + (size_t)rr*512 + seg*32 + i*8);
    bf16x8 b1reg[4];
    { int n=(0*8+wid)*16+l15;
      #pragma unroll
      for (int kk=0;kk<4;kk++)
        b1reg[kk]=*(const bf16x8*)(w1l + (size_t)n*H + kk*32 + l4*8);
    }

    // ---- LN2 -> hlb (wave-local rows; hlb readers done pre-barrier)
    ln_block(tokacc, hlb, ln2_g+ll*H, ln2_b+ll*H, rowb, l15);

    // ---- FF: 4 K-chunks; FF1 (B pipelined) -> chA; FF2 (B = wst, async-staged)
    { f32x4 fac[8];
      #pragma unroll
      for (int nt=0;nt<8;nt++) fac[nt]=(f32x4){0.f,0.f,0.f,0.f};
      for (int c0i=0;c0i<4;c0i++){
        __syncthreads();   // prev FF2 done with wst; chA consumed; hlb(LN2) visible
        // write staged Wff2 chunk c0i -> wst (loads issued one full chunk earlier)
        #pragma unroll
        for (int i=0;i<4;i++)
          *(bf16x8*)(wst + rr*S1 + seg*32 + i*8) = w2reg[i];
        // issue Wff2 loads for chunk c0i+1 (hide under FF1 + FF2)
        if (c0i<3){
          #pragma unroll
          for (int i=0;i<4;i++)
            w2reg[i]=*(const bf16x8*)(w2l + (size_t)rr*512 + (c0i+1)*128 + seg*32 + i*8);
        }
        // FF1: wave computes feature tile c0i*8+wid for all 8 mt -> chA
        { float bias1=ff1_b[ll*512+(c0i*8+wid)*16+l15];
          for (int mt=0;mt<8;mt++){
            f32x4 c={0.f,0.f,0.f,0.f};
            #pragma unroll
            for (int kk=0;kk<4;kk++){
              bf16x8 a=*(const bf16x8*)(hlb + (mt*16+l15)*S1 + kk*32 + l4*8);
              c=__builtin_amdgcn_mfma_f32_16x16x32_bf16(a,b1reg[kk],c,0,0,0);
            }
            int rb=mt*16+l4*4;
            #pragma unroll
            for (int reg=0;reg<4;reg++)
              chA[(rb+reg)*S1 + wid*16+l15]=f2b(fmaxf(c[reg]+bias1,0.f));
          }
        }
        // issue FF1 B loads for chunk c0i+1 (b1reg free; hide under barrier+FF2)
        if (c0i<3){
          int n2=((c0i+1)*8+wid)*16+l15;
          #pragma unroll
          for (int kk=0;kk<4;kk++)
            b1reg[kk]=*(const bf16x8*)(w1l + (size_t)n2*H + kk*32 + l4*8);
        }
        __syncthreads();
        // FF2 partial: A = chA own stripe; B = wst
        { bf16x8 a2[4];
          #pragma unroll
          for (int kk=0;kk<4;kk++)
            a2[kk]=*(const bf16x8*)(chA + (wid*16+l15)*S1 + kk*32 + l4*8);
          #pragma unroll
          for (int nt=0;nt<8;nt++){
            int n2=nt*16+l15;
            #pragma unroll
            for (int kk=0;kk<4;kk++){
              bf16x8 bb=*(const bf16x8*)(wst + n2*S1 + kk*32 + l4*8);
              fac[nt]=__builtin_amdgcn_mfma_f32_16x16x32_bf16(a2[kk],bb,fac[nt],0,0,0);
            }
          }
        }
      }
      #pragma unroll
      for (int nt=0;nt<8;nt++){
        float b2v=ff2_b[ll*H + nt*16+l15];
        #pragma unroll
        for (int reg=0;reg<4;reg++) tokacc[nt][reg]+=fac[nt][reg]+b2v;
      }
    }
    __syncthreads();  // all waves done with wst/chA/hlb before next layer's LN1
  }

  // ---- final LN on token-0 rows (reg==0), compact to hlb rows 0..31
  { float s=0.f,q=0.f;
    #pragma unroll
    for (int nt=0;nt<8;nt++){ float v=tokacc[nt][0]; s+=v; q+=v*v; }
    #pragma unroll
    for (int m=1;m<16;m<<=1){ s+=__shfl_xor(s,m); q+=__shfl_xor(q,m); }
    float mean=s*(1.f/128.f);
    float rs=rsqrtf(q*(1.f/128.f)-mean*mean+1e-5f);
    int ci=wid*4+l4;
    #pragma unroll
    for (int nt=0;nt<8;nt++){
      int col=nt*16+l15;
      float hv=(tokacc[nt][0]-mean)*rs*fin_g[col]+fin_b[col];
      hlb[ci*S1+col]=f2b(hv);
    }
  }
  __syncthreads();

  // ---- head GEMM1 [32x128]@hw1^T + gelu
  float gel[2][4];
  { int n=wid*16+l15;
    bf16x8 bh[4];
    #pragma unroll
    for (int kk=0;kk<4;kk++)
      bh[kk]=*(const bf16x8*)(hw1b + (size_t)n*H + kk*32 + l4*8);
    float hb1v=hb1[n];
    #pragma unroll
    for (int mt=0;mt<2;mt++){
      f32x4 c={0.f,0.f,0.f,0.f};
      #pragma unroll
      for (int kk=0;kk<4;kk++){
        bf16x8 a=*(const bf16x8*)(hlb + (mt*16+l15)*S1 + kk*32 + l4*8);
        c=__builtin_amdgcn_mfma_f32_16x16x32_bf16(a,bh[kk],c,0,0,0);
      }
      #pragma unroll
      for (int reg=0;reg<4;reg++){
        float xx=c[reg]+hb1v;
        gel[mt][reg]=0.5f*xx*(1.f+erff(xx*0.70710678118654752f));
      }
    }
  }
  // ---- head LN (cross-wave)
  #pragma unroll
  for (int mt=0;mt<2;mt++){
    #pragma unroll
    for (int reg=0;reg<4;reg++){
      float v=gel[mt][reg], sv=v, qv=v*v;
      #pragma unroll
      for (int m=1;m<16;m<<=1){ sv+=__shfl_xor(sv,m); qv+=__shfl_xor(qv,m); }
      if (l15==0){ int r32=mt*16+l4*4+reg; red_s[r32*8+wid]=sv; red_q[r32*8+wid]=qv; }
    }
  }
  __syncthreads();
  if (tid<32){
    float ss=0.f,qs=0.f;
    #pragma unroll
    for (int w=0;w<8;w++){ ss+=red_s[tid*8+w]; qs+=red_q[tid*8+w]; }
    float mm=ss*(1.f/128.f);
    stat_m[tid]=mm;
    stat_r[tid]=rsqrtf(qs*(1.f/128.f)-mm*mm+1e-5f);
  }
  __syncthreads();
  { int n=wid*16+l15;
    float hg=hlng[n], hbv=hlnb[n];
    #pragma unroll
    for (int mt=0;mt<2;mt++){
      #pragma unroll
      for (int reg=0;reg<4;reg++){
        int r32=mt*16+l4*4+reg;
        float z=(gel[mt][reg]-stat_m[r32])*stat_r[r32]*hg+hbv;
        hlb[r32*S1+n]=f2b(z);
      }
    }
  }
  __syncthreads();

  // ---- head GEMM2 [32x128] @ hw2^T -> out (waves 0,1)
  if (wid<2){
    int mt=wid;
    bool valid=l15<10;
    bf16x8 b2[4];
    #pragma unroll
    for (int kk=0;kk<4;kk++){
      if (valid) b2[kk]=*(const bf16x8*)(hw2b + (size_t)l15*H + kk*32 + l4*8);
      else { bf16x8 z; for (int t=0;t<8;t++) z[t]=0; b2[kk]=z; }
    }
    f32x4 c={0.f,0.f,0.f,0.f};
    #pragma unroll
    for (int kk=0;kk<4;kk++){
      bf16x8 av=*(const bf16x8*)(hlb + (mt*16+l15)*S1 + kk*32 + l4*8);
      c=__builtin_amdgcn_mfma_f32_16x16x32_bf16(av,b2[kk],c,0,0,0);
    }
    if (valid){
      float bb2=hb2[l15];
      #pragma unroll
      for (int reg=0;reg<4;reg++){
        int i=mt*16+l4*4+reg;
        out[((size_t)node0+i)*10 + l15]=c[reg]+bb2;
      }
    }
  }
}

extern "C" void kernel_launch(void* const* d_in, const int* in_sizes, int n_in,
                              void* d_out, int out_size, void* d_ws, size_t ws_size,
                              hipStream_t stream){
  const float* x       =(const float*)d_in[0];
  const int*   ei      =(const int*)  d_in[1];
  const float* eigvecs =(const float*)d_in[2];
  const float* eigvals =(const float*)d_in[3];
  const float* enc_w   =(const float*)d_in[4];
  const float* enc_b   =(const float*)d_in[5];
  const float* in_ln_g =(const float*)d_in[6];
  const float* in_ln_b =(const float*)d_in[7];
  const float* pe_phi_w1=(const float*)d_in[8];
  const float* pe_phi_w2=(const float*)d_in[9];
  const float* pe_rho_w1=(const float*)d_in[10];
  const float* pe_rho_b1=(const float*)d_in[11];
  const float* pe_rho_w2=(const float*)d_in[12];
  const float* pe_rho_b2=(const float*)d_in[13];
  const float* pe_eps  =(const float*)d_in[14];
  const float* hop_emb =(const float*)d_in[15];
  const float* qkv_w   =(const float*)d_in[16];
  const float* qkv_b   =(const float*)d_in[17];
  const float* out_w   =(const float*)d_in[18];
  const float* out_b   =(const float*)d_in[19];
  const float* ln1_g   =(const float*)d_in[20];
  const float* ln1_b   =(const float*)d_in[21];
  const float* ln2_g   =(const float*)d_in[22];
  const float* ln2_b   =(const float*)d_in[23];
  const float* ff1_w   =(const float*)d_in[24];
  const float* ff1_b   =(const float*)d_in[25];
  const float* ff2_w   =(const float*)d_in[26];
  const float* ff2_b   =(const float*)d_in[27];
  const float* fin_g   =(const float*)d_in[28];
  const float* fin_b   =(const float*)d_in[29];
  const float* hw1     =(const float*)d_in[30];
  const float* hb1     =(const float*)d_in[31];
  const float* hlg     =(const float*)d_in[32];
  const float* hlb_    =(const float*)d_in[33];
  const float* hw2     =(const float*)d_in[34];
  const float* hb2     =(const float*)d_in[35];

  char* ws=(char*)d_ws;
  size_t off=0;
  auto alloc=[&](size_t bytes)->void*{
    void* p=ws+off;
    off+=(bytes+255)&~(size_t)255;
    return p;
  };
  ushort* tokens=(ushort*)alloc((size_t)NN*4*H*sizeof(ushort));  // 102.4 MB bf16
  float* deg    =(float*)alloc((size_t)NN*sizeof(float));
  int*   counts =(int*)  alloc((size_t)NN*sizeof(int));
  int*   row_ptr=(int*)  alloc((size_t)(NN+1)*sizeof(int));
  int*   cursor =(int*)  alloc((size_t)NN*sizeof(int));
  int*   cs_col =(int*)  alloc((size_t)EE*sizeof(int));
  float* cs_w   =(float*)alloc((size_t)EE*sizeof(float));
  int*   flag   =(int*)  alloc(256);
  int*   bsum   =(int*)  alloc(64*sizeof(int));
  ushort* wqkvb =(ushort*)alloc((size_t)2*384*H*sizeof(ushort));
  ushort* woutb =(ushort*)alloc((size_t)2*H*H*sizeof(ushort));
  ushort* wff1b =(ushort*)alloc((size_t)2*512*H*sizeof(ushort));
  ushort* wff2b =(ushort*)alloc((size_t)2*H*512*sizeof(ushort));
  ushort* hw1b  =(ushort*)alloc((size_t)H*H*sizeof(ushort));
  ushort* hw2b  =(ushort*)alloc((size_t)10*H*sizeof(ushort));
  ushort* wpw2b =(ushort*)alloc((size_t)H*H*sizeof(ushort));
  ushort* wrw1b =(ushort*)alloc((size_t)H*H*sizeof(ushort));
  ushort* wrw2b =(ushort*)alloc((size_t)H*H*sizeof(ushort));
  ushort* wencb =(ushort*)alloc((size_t)H*H*sizeof(ushort));
  if (off>ws_size) return;

  const int NB=(NN+SCB-1)/SCB;   // 25 scan blocks

  hipMemsetAsync(deg,0,(size_t)NN*sizeof(float),stream);
  hipMemsetAsync(counts,0,(size_t)NN*sizeof(int),stream);
  detect_kernel<<<1,256,0,stream>>>(ei,flag);

  // single fused weight-conversion launch
  CvtArgs ca;
  const float* srcs[10]={qkv_w,out_w,ff1_w,ff2_w,hw1,hw2,pe_phi_w2,pe_rho_w1,pe_rho_w2,enc_w};
  ushort* dsts[10]={wqkvb,woutb,wff1b,wff2b,hw1b,hw2b,wpw2b,wrw1b,wrw2b,wencb};
  int ns[10]={2*384*H,2*H*H,2*512*H,2*H*512,H*H,10*H,H*H,H*H,H*H,H*H};
  int acc=0;
  for (int i=0;i<10;i++){ ca.src[i]=srcs[i]; ca.dst[i]=dsts[i]; ca.off[i]=acc; acc+=ns[i]; }
  ca.off[10]=acc;
  cvtall_kernel<<<(acc+255)/256,256,0,stream>>>(ca);

  enc2_kernel<<<(NN+127)/128,512,0,stream>>>(x,wencb,enc_b,in_ln_g,in_ln_b,tokens);
  hist_kernel<<<(EE+255)/256,256,0,stream>>>(ei,flag,deg,counts);
  dinv_kernel<<<(NN+255)/256,256,0,stream>>>(deg);
  scanp1_kernel<<<NB,1024,0,stream>>>(counts,bsum);
  scanp2_kernel<<<1,64,0,stream>>>(bsum,NB,row_ptr);
  scanp3_kernel<<<NB,1024,0,stream>>>(counts,bsum,row_ptr,cursor);
  scatter_kernel<<<(EE+255)/256,256,0,stream>>>(ei,flag,cursor,deg,cs_col,cs_w);
  for (int k=0;k<3;k++)
    spmm2_kernel<<<NN/8,256,0,stream>>>(tokens,row_ptr,cs_col,cs_w,k);
  pe2_kernel<<<(NN+127)/128,512,0,stream>>>(eigvecs,eigvals,pe_phi_w1,pe_eps,
                                            wpw2b,wrw1b,pe_rho_b1,wrw2b,pe_rho_b2,
                                            tokens);
  xform8_kernel<<<NN/32,512,0,stream>>>(tokens,hop_emb,
                                        wqkvb,qkv_b,woutb,out_b,
                                        ln1_g,ln1_b,ln2_g,ln2_b,
                                        wff1b,ff1_b,wff2b,ff2_b,
                                        fin_g,fin_b,hw1b,hb1,hlg,hlb_,hw2b,hb2,
                                        (float*)d_out);
}